// Round 7
// baseline (760.599 us; speedup 1.0000x reference)
//
#include <hip/hip_runtime.h>

// ---------------------------------------------------------------------------
// Transformer block w/ SimilarityMaps branch. fp32 inputs/outputs; weights
// canonicalized to bf16; GEMMs + attention on MFMA (16x16x32 bf16).
// B=8 N=1024 C=768 H=12 hd=64 K_PARTS=64 HID=3072. Tokens M = 8192.
// Round 6: vectorized GEMM epilogue via LDS repack (was 64 scalar u16 stores).
// ---------------------------------------------------------------------------

typedef unsigned short u16;
typedef unsigned int   u32;
typedef __attribute__((ext_vector_type(8))) short short8;       // bf16 x8 frag
typedef __attribute__((ext_vector_type(8))) unsigned short ushort8v;
typedef __attribute__((ext_vector_type(4))) float f32x4;        // MFMA accum

#define F_GELU     1
#define F_ROWSCALE 2
#define F_RES1     4    // bf16 residual (res1)
#define F_RESF     8    // fp32 residual (resf)
#define F_OUTB     16   // write bf16 to out
#define F_OUTF     32   // write fp32 to outf
#define F_BIAS     64   // fp32 bias

__device__ __forceinline__ float bf2f(u32 b) { return __uint_as_float(b << 16); }
__device__ __forceinline__ u16 f2bf(float f) {
    u32 u = __float_as_uint(f);
    u32 r = u + 0x7fffu + ((u >> 16) & 1u);   // RNE
    return (u16)(r >> 16);
}
__device__ __forceinline__ u16 f2bf_fast(float f) {
    return (u16)((__float_as_uint(f) + 0x8000u) >> 16);
}
__device__ __forceinline__ float gelu_exact(float v) {
    return 0.5f * v * (1.0f + erff(v * 0.70710678118654752440f));
}

// async global->LDS, 16 B per lane; lds base must be wave-uniform
__device__ __forceinline__ void gload16(const u16* g, u16* l) {
    __builtin_amdgcn_global_load_lds(
        (const __attribute__((address_space(1))) u32*)g,
        (__attribute__((address_space(3))) u32*)l, 16, 0, 0);
}

// ---------------- fp32 -> bf16 weight canonicalization ---------------------
__global__ __launch_bounds__(256)
void conv_k(const float* __restrict__ src, u16* __restrict__ dst, int n)
{
    const int base = (blockIdx.x * 256 + threadIdx.x) * 4;
    if (base >= n) return;
    float4 v = *(const float4*)(src + base);
    ushort4 o;
    o.x = f2bf(v.x); o.y = f2bf(v.y); o.z = f2bf(v.z); o.w = f2bf(v.w);
    *(ushort4*)(dst + base) = o;
}

__device__ __forceinline__ float block_sum(float v, float* red) {
    #pragma unroll
    for (int off = 32; off > 0; off >>= 1) v += __shfl_down(v, off);
    __syncthreads();
    if ((threadIdx.x & 63) == 0) red[threadIdx.x >> 6] = v;
    __syncthreads();
    return red[0] + red[1] + red[2] + red[3];
}

// ---------------- LayerNorm over 768 (fp32 in, bf16 out), opt 1/||y|| ------
template<bool NORM>
__global__ __launch_bounds__(256)
void ln_k(const float* __restrict__ xin, const float* __restrict__ g,
          const float* __restrict__ bta, u16* __restrict__ out,
          float* __restrict__ invnorm)
{
    __shared__ float red[4];
    const int row = blockIdx.x, t = threadIdx.x;
    float v[3];
    #pragma unroll
    for (int i = 0; i < 3; i++)
        v[i] = xin[(size_t)row * 768 + t + i * 256];
    float tot = block_sum(v[0] + v[1] + v[2], red);
    float mu  = tot * (1.0f / 768.0f);
    float d0 = v[0] - mu, d1 = v[1] - mu, d2 = v[2] - mu;
    float tot2 = block_sum(d0 * d0 + d1 * d1 + d2 * d2, red);
    float rstd = rsqrtf(tot2 * (1.0f / 768.0f) + 1e-5f);
    float ss = 0.0f;
    #pragma unroll
    for (int i = 0; i < 3; i++) {
        int c = t + i * 256;
        float yy = (v[i] - mu) * rstd * g[c] + bta[c];
        out[(size_t)row * 768 + c] = f2bf(yy);
        ss += yy * yy;
    }
    if constexpr (NORM) {
        float tot3 = block_sum(ss, red);
        if (t == 0) invnorm[row] = rsqrtf(tot3);
    }
}

// ---------------- P row-normalize: Pn = bf16(P / ||P_row||) ----------------
__global__ __launch_bounds__(256)
void pn_k(const float* __restrict__ P, u16* __restrict__ Pn)
{
    __shared__ float red[4];
    const int row = blockIdx.x, t = threadIdx.x;
    float v[3];
    #pragma unroll
    for (int i = 0; i < 3; i++)
        v[i] = P[(size_t)row * 768 + t + i * 256];
    float tot = block_sum(v[0]*v[0] + v[1]*v[1] + v[2]*v[2], red);
    float inv = rsqrtf(tot);
    #pragma unroll
    for (int i = 0; i < 3; i++)
        Pn[(size_t)row * 768 + t + i * 256] = f2bf(v[i] * inv);
}

// ---------------- MFMA GEMM: C[M,N] = A[M,K] * W[N,K]^T (+epilogue) --------
// 128x128 tile, BK=32; 4 waves, each a 64x64 sub-tile. LDS-repacked epilogue.
template<int FLAGS>
__global__ __launch_bounds__(256)
void gemm_mfma(const u16* __restrict__ A, const u16* __restrict__ W,
               const float* __restrict__ bias,
               const u16* __restrict__ res1, const float* __restrict__ resf,
               u16* __restrict__ out, float* __restrict__ outf,
               int M, int N, int K)
{
    __shared__ u16 smem[8704];           // staging: As[0:4096) Bs[4096:8192)
                                         // epilogue: Cs 64 rows x 136 u16
    const int t = threadIdx.x;
    const int wave = t >> 6, lane = t & 63;
    const int m0 = blockIdx.y * 128, n0 = blockIdx.x * 128;
    const int Wm = (wave >> 1) * 64, Wn = (wave & 1) * 64;
    const int rr = lane >> 2, cc = (lane & 3) * 8;
    const int quad = lane >> 4, r16 = lane & 15;

    f32x4 acc[4][4];
    #pragma unroll
    for (int i = 0; i < 4; i++)
        #pragma unroll
        for (int j = 0; j < 4; j++)
            acc[i][j] = (f32x4){0.f, 0.f, 0.f, 0.f};

    for (int k0 = 0; k0 < K; k0 += 32) {
        #pragma unroll
        for (int c = 0; c < 2; c++) {
            const int chunk = wave * 2 + c;
            const int row = chunk * 16 + rr;
            gload16(A + (size_t)(m0 + row) * K + k0 + cc, &smem[chunk * 512]);
            gload16(W + (size_t)(n0 + row) * K + k0 + cc, &smem[4096 + chunk * 512]);
        }
        __syncthreads();
        short8 af[4], bfr[4];
        #pragma unroll
        for (int i = 0; i < 4; i++) {
            af[i]  = *(const short8*)&smem[(Wm + i * 16 + r16) * 32 + quad * 8];
            bfr[i] = *(const short8*)&smem[4096 + (Wn + i * 16 + r16) * 32 + quad * 8];
        }
        #pragma unroll
        for (int i = 0; i < 4; i++)
            #pragma unroll
            for (int j = 0; j < 4; j++)
                acc[i][j] = __builtin_amdgcn_mfma_f32_16x16x32_bf16(
                    af[i], bfr[j], acc[i][j], 0, 0, 0);
        __syncthreads();
    }

    // ---- bias + gelu in C/D layout (col = Wn + j*16 + r16) ----
    #pragma unroll
    for (int j = 0; j < 4; j++) {
        float bj = 0.0f;
        if constexpr (FLAGS & F_BIAS) bj = bias[n0 + Wn + j * 16 + r16];
        #pragma unroll
        for (int i = 0; i < 4; i++)
            #pragma unroll
            for (int r = 0; r < 4; r++) {
                float v = acc[i][j][r] + bj;
                if constexpr (FLAGS & F_GELU) v = gelu_exact(v);
                acc[i][j][r] = v;
            }
    }

    // ---- LDS repack (2 halves of 64 rows), then coalesced 16B stores ----
    const int halfmine = wave >> 1;
    #pragma unroll
    for (int half = 0; half < 2; half++) {
        if (halfmine == half) {
            #pragma unroll
            for (int i = 0; i < 4; i++)
                #pragma unroll
                for (int j = 0; j < 4; j++) {
                    const int col = Wn + j * 16 + r16;
                    #pragma unroll
                    for (int r = 0; r < 4; r++) {
                        const int rowl = i * 16 + quad * 4 + r;
                        smem[rowl * 136 + col] = f2bf(acc[i][j][r]);
                    }
                }
        }
        __syncthreads();
        #pragma unroll
        for (int pass = 0; pass < 4; pass++) {
            const int rowl = pass * 16 + (t >> 4);
            const int col  = (t & 15) * 8;
            const int m = m0 + half * 64 + rowl;
            const size_t idx = (size_t)m * N + n0 + col;
            ushort8v pv = *(const ushort8v*)&smem[rowl * 136 + col];
            if constexpr ((FLAGS & (F_RES1 | F_RESF)) == 0) {
                if constexpr (FLAGS & F_OUTB)
                    *(ushort8v*)(out + idx) = pv;
                if constexpr (FLAGS & F_OUTF) {
                    float4 o0 = {bf2f(pv[0]), bf2f(pv[1]), bf2f(pv[2]), bf2f(pv[3])};
                    float4 o1 = {bf2f(pv[4]), bf2f(pv[5]), bf2f(pv[6]), bf2f(pv[7])};
                    *(float4*)(outf + idx) = o0;
                    *(float4*)(outf + idx + 4) = o1;
                }
            } else {
                float v[8];
                #pragma unroll
                for (int k = 0; k < 8; k++) v[k] = bf2f(pv[k]);
                if constexpr (FLAGS & F_RES1) {
                    ushort8v rv = *(const ushort8v*)(res1 + idx);
                    #pragma unroll
                    for (int k = 0; k < 8; k++) v[k] += bf2f(rv[k]);
                }
                if constexpr (FLAGS & F_RESF) {
                    float4 r0 = *(const float4*)(resf + idx);
                    float4 r1 = *(const float4*)(resf + idx + 4);
                    v[0] += r0.x; v[1] += r0.y; v[2] += r0.z; v[3] += r0.w;
                    v[4] += r1.x; v[5] += r1.y; v[6] += r1.z; v[7] += r1.w;
                }
                if constexpr (FLAGS & F_OUTB) {
                    ushort8v o;
                    #pragma unroll
                    for (int k = 0; k < 8; k++) o[k] = f2bf(v[k]);
                    *(ushort8v*)(out + idx) = o;
                }
                if constexpr (FLAGS & F_OUTF) {
                    float4 o0 = {v[0], v[1], v[2], v[3]};
                    float4 o1 = {v[4], v[5], v[6], v[7]};
                    *(float4*)(outf + idx) = o0;
                    *(float4*)(outf + idx + 4) = o1;
                }
            }
        }
        __syncthreads();
    }
}

// ---------------- small fp32 GEMM (64x64 tiles) for the K-parts branch -----
template<int BM, int BN, int FLAGS>
__global__ __launch_bounds__(256)
void gemm_k(const u16* __restrict__ A, const u16* __restrict__ W,
            const float* __restrict__ bias, const float* __restrict__ rowscale,
            const u16* __restrict__ res1, const float* __restrict__ resf,
            u16* __restrict__ out, float* __restrict__ outf,
            int M, int N, int K)
{
    constexpr int RM = BM / 16, RN = BN / 16;
    __shared__ float Asm[16][BM + 4];
    __shared__ float Wsm[16][BN + 4];
    const int t  = threadIdx.x;
    const int tx = t & 15, ty = t >> 4;
    const int m0 = blockIdx.y * BM, n0 = blockIdx.x * BN;

    float acc[RM][RN];
    #pragma unroll
    for (int i = 0; i < RM; i++)
        #pragma unroll
        for (int j = 0; j < RN; j++) acc[i][j] = 0.0f;

    for (int k0 = 0; k0 < K; k0 += 16) {
        #pragma unroll
        for (int i = 0; i < BM / 64; i++) {
            int f = t + i * 256, r = f >> 2, c4 = (f & 3) << 2;
            uint2 u = *(const uint2*)(A + (size_t)(m0 + r) * K + k0 + c4);
            Asm[c4 + 0][r] = bf2f(u.x & 0xffffu);
            Asm[c4 + 1][r] = bf2f(u.x >> 16);
            Asm[c4 + 2][r] = bf2f(u.y & 0xffffu);
            Asm[c4 + 3][r] = bf2f(u.y >> 16);
        }
        #pragma unroll
        for (int i = 0; i < BN / 64; i++) {
            int f = t + i * 256, r = f >> 2, c4 = (f & 3) << 2;
            uint2 u = *(const uint2*)(W + (size_t)(n0 + r) * K + k0 + c4);
            Wsm[c4 + 0][r] = bf2f(u.x & 0xffffu);
            Wsm[c4 + 1][r] = bf2f(u.x >> 16);
            Wsm[c4 + 2][r] = bf2f(u.y & 0xffffu);
            Wsm[c4 + 3][r] = bf2f(u.y >> 16);
        }
        __syncthreads();
        #pragma unroll
        for (int k = 0; k < 16; k++) {
            float a[RM], w[RN];
            #pragma unroll
            for (int ii = 0; ii < RM; ii += 4) {
                float4 v = *(const float4*)&Asm[k][ty * RM + ii];
                a[ii] = v.x; a[ii + 1] = v.y; a[ii + 2] = v.z; a[ii + 3] = v.w;
            }
            #pragma unroll
            for (int jj = 0; jj < RN; jj += 4) {
                float4 v = *(const float4*)&Wsm[k][tx * RN + jj];
                w[jj] = v.x; w[jj + 1] = v.y; w[jj + 2] = v.z; w[jj + 3] = v.w;
            }
            #pragma unroll
            for (int i = 0; i < RM; i++)
                #pragma unroll
                for (int j = 0; j < RN; j++)
                    acc[i][j] = fmaf(a[i], w[j], acc[i][j]);
        }
        __syncthreads();
    }

    #pragma unroll
    for (int i = 0; i < RM; i++) {
        const int m = m0 + ty * RM + i;
        float rs = 1.0f;
        if constexpr (FLAGS & F_ROWSCALE) rs = rowscale[m];
        #pragma unroll
        for (int jj = 0; jj < RN; jj += 4) {
            const int n = n0 + tx * RN + jj;
            const size_t idx = (size_t)m * N + n;
            float b4[4] = {0.f, 0.f, 0.f, 0.f};
            if constexpr (FLAGS & F_BIAS) {
                float4 bvv = *(const float4*)(bias + n);
                b4[0] = bvv.x; b4[1] = bvv.y; b4[2] = bvv.z; b4[3] = bvv.w;
            }
            float e[4];
            #pragma unroll
            for (int j = 0; j < 4; j++) {
                float v = acc[i][jj + j];
                if constexpr (FLAGS & F_BIAS) v += b4[j];
                if constexpr (FLAGS & F_GELU) v = gelu_exact(v);
                if constexpr (FLAGS & F_ROWSCALE) v *= rs;
                e[j] = v;
            }
            if constexpr (FLAGS & F_OUTB) {
                ushort4 o4;
                o4.x = f2bf(e[0]); o4.y = f2bf(e[1]);
                o4.z = f2bf(e[2]); o4.w = f2bf(e[3]);
                *(ushort4*)(out + idx) = o4;
            }
            if constexpr (FLAGS & F_OUTF) {
                float4 o4 = {e[0], e[1], e[2], e[3]};
                *(float4*)(outf + idx) = o4;
            }
        }
    }
}

// ---------------- MFMA flash attention (bf16, max-free online softmax) ----
__global__ __launch_bounds__(256)
void attn_mfma(const u16* __restrict__ qkv, u16* __restrict__ out)
{
    const int qt = blockIdx.x;            // 0..7  (128-row q tiles)
    const int bh = blockIdx.y;            // 0..95
    const int b = bh / 12, h = bh % 12;
    __shared__ u16 Qs[2 * 128 * 32];      // 16 KB
    __shared__ u16 Ks[2 * 64 * 32];       //  8 KB
    __shared__ u16 Vt[2 * 64 * 32];       //  8 KB  (transposed: rows = d)
    __shared__ u16 Ps[2 * 128 * 32];      // 16 KB
    const int t = threadIdx.x;
    const int wave = t >> 6, lane = t & 63;
    const int quad = lane >> 4, r16 = lane & 15;
    const size_t RS = 2304;
    const int tok0 = b * 1024 + qt * 128;
    const u16* qbase = qkv + (size_t)tok0 * RS + h * 64;
    const float SC = 0.125f * 1.44269504088896340736f;   // scale * log2(e)

    #pragma unroll
    for (int c = 0; c < 4; c++) {
        int idx = wave * 4 + c;
        int kc = idx >> 3, rg = idx & 7;
        int row = rg * 16 + (lane >> 2);
        gload16(qbase + (size_t)row * RS + kc * 32 + (lane & 3) * 8,
                &Qs[kc * 4096 + rg * 512]);
    }

    f32x4 O[2][4];
    float lpart[2][4];
    #pragma unroll
    for (int i = 0; i < 2; i++)
        #pragma unroll
        for (int j = 0; j < 4; j++) {
            O[i][j] = (f32x4){0.f, 0.f, 0.f, 0.f};
            lpart[i][j & 3] = 0.0f;
        }

    for (int kt = 0; kt < 16; kt++) {
        const u16* kbase = qkv + (size_t)(b * 1024 + kt * 64) * RS + 768 + h * 64;
        #pragma unroll
        for (int c = 0; c < 2; c++) {
            int idx = wave * 2 + c;
            int kc = idx >> 2, rg = idx & 3;
            int row = rg * 16 + (lane >> 2);
            gload16(kbase + (size_t)row * RS + kc * 32 + (lane & 3) * 8,
                    &Ks[kc * 2048 + rg * 512]);
        }
        const u16* vbase = qkv + (size_t)(b * 1024 + kt * 64) * RS + 1536 + h * 64;
        {
            const int kp = t & 63, dg = t >> 6;
            const int vb = (kp >> 5) * 2048 + (kp & 31);
            #pragma unroll
            for (int it = 0; it < 4; it++) {
                int d0 = dg * 16 + it * 4;
                uint2 u = *(const uint2*)(vbase + (size_t)kp * RS + d0);
                Vt[vb + (d0 + 0) * 32] = (u16)(u.x & 0xffffu);
                Vt[vb + (d0 + 1) * 32] = (u16)(u.x >> 16);
                Vt[vb + (d0 + 2) * 32] = (u16)(u.y & 0xffffu);
                Vt[vb + (d0 + 3) * 32] = (u16)(u.y >> 16);
            }
        }
        __syncthreads();

        f32x4 S[2][4];
        #pragma unroll
        for (int i = 0; i < 2; i++)
            #pragma unroll
            for (int j = 0; j < 4; j++)
                S[i][j] = (f32x4){0.f, 0.f, 0.f, 0.f};
        #pragma unroll
        for (int kc = 0; kc < 2; kc++) {
            short8 aq[2], bk[4];
            #pragma unroll
            for (int i = 0; i < 2; i++)
                aq[i] = *(const short8*)&Qs[kc * 4096 + (wave * 32 + i * 16 + r16) * 32 + quad * 8];
            #pragma unroll
            for (int j = 0; j < 4; j++)
                bk[j] = *(const short8*)&Ks[kc * 2048 + (j * 16 + r16) * 32 + quad * 8];
            #pragma unroll
            for (int i = 0; i < 2; i++)
                #pragma unroll
                for (int j = 0; j < 4; j++)
                    S[i][j] = __builtin_amdgcn_mfma_f32_16x16x32_bf16(
                        aq[i], bk[j], S[i][j], 0, 0, 0);
        }

        #pragma unroll
        for (int i = 0; i < 2; i++) {
            #pragma unroll
            for (int j = 0; j < 4; j++) {
                const int col = j * 16 + r16;
                const int pb = (col >> 5) * 4096 + (col & 31);
                #pragma unroll
                for (int r = 0; r < 4; r++) {
                    float p = __builtin_amdgcn_exp2f(S[i][j][r] * SC);
                    lpart[i][r] += p;
                    const int row = wave * 32 + i * 16 + quad * 4 + r;
                    Ps[pb + row * 32] = f2bf_fast(p);
                }
            }
        }

        #pragma unroll
        for (int kc = 0; kc < 2; kc++) {
            short8 ap[2], bv[4];
            #pragma unroll
            for (int i = 0; i < 2; i++)
                ap[i] = *(const short8*)&Ps[kc * 4096 + (wave * 32 + i * 16 + r16) * 32 + quad * 8];
            #pragma unroll
            for (int j = 0; j < 4; j++)
                bv[j] = *(const short8*)&Vt[kc * 2048 + (j * 16 + r16) * 32 + quad * 8];
            #pragma unroll
            for (int i = 0; i < 2; i++)
                #pragma unroll
                for (int j = 0; j < 4; j++)
                    O[i][j] = __builtin_amdgcn_mfma_f32_16x16x32_bf16(
                        ap[i], bv[j], O[i][j], 0, 0, 0);
        }
        __syncthreads();
    }

    #pragma unroll
    for (int i = 0; i < 2; i++) {
        float linv[4];
        #pragma unroll
        for (int r = 0; r < 4; r++) {
            float l = lpart[i][r];
            l += __shfl_xor(l, 1);
            l += __shfl_xor(l, 2);
            l += __shfl_xor(l, 4);
            l += __shfl_xor(l, 8);
            linv[r] = 1.0f / l;
        }
        #pragma unroll
        for (int r = 0; r < 4; r++) {
            const int token = tok0 + wave * 32 + i * 16 + quad * 4 + r;
            #pragma unroll
            for (int j = 0; j < 4; j++) {
                const int d = j * 16 + r16;
                out[(size_t)token * 768 + h * 64 + d] = f2bf(O[i][j][r] * linv[r]);
            }
        }
    }
}

// ---------------------------------------------------------------------------
extern "C" void kernel_launch(void* const* d_in, const int* in_sizes, int n_in,
                              void* d_out, int out_size, void* d_ws, size_t ws_size,
                              hipStream_t stream)
{
    (void)in_sizes; (void)n_in; (void)out_size; (void)ws_size;
    const float* x        = (const float*)d_in[0];
    const float* ln1_g    = (const float*)d_in[1];
    const float* ln1_b    = (const float*)d_in[2];
    const float* qkv_w    = (const float*)d_in[3];
    const float* qkv_b    = (const float*)d_in[4];
    const float* proj_w   = (const float*)d_in[5];
    const float* proj_b   = (const float*)d_in[6];
    const float* c_qkv_w  = (const float*)d_in[7];
    const float* c_qkv_b  = (const float*)d_in[8];
    const float* c_proj_w = (const float*)d_in[9];
    const float* c_proj_b = (const float*)d_in[10];
    const float* cp_fc1_w = (const float*)d_in[11];
    const float* cp_fc1_b = (const float*)d_in[12];
    const float* cp_fc2_w = (const float*)d_in[13];
    const float* cp_fc2_b = (const float*)d_in[14];
    const float* P        = (const float*)d_in[15];
    const float* ln2_g    = (const float*)d_in[16];
    const float* ln2_b    = (const float*)d_in[17];
    const float* fc1_w    = (const float*)d_in[18];
    const float* fc1_b    = (const float*)d_in[19];
    const float* fc2_w    = (const float*)d_in[20];
    const float* fc2_b    = (const float*)d_in[21];

    float* out_x    = (float*)d_out;               // (8,1024,768) fp32
    float* out_dmap = out_x + 6291456;             // (8,1024,64)  fp32

    // ws layout (u16 element units)
    u16* us    = (u16*)d_ws;
    u16* n1n2  = us;                         //  6291456  n1 -> zin -> n2
    u16* bigA  = us + 6291456;               // 25165824  qkv/qkv2 ; h(3072)
    u16* ao    = bigA + 18874368;            //  6291456  attn out (tail)
    u16* y     = us + 31457280;              //  6291456
    float* xs  = (float*)(us + 37748736);    //  6291456 fp32
    u16* dmapb = us + 50331648;              //   524288
    u16* cph   = us + 50855936;              //   524288
    u16* Pn    = us + 51380224;              //    49152
    float* invn = (float*)(us + 51429376);   //  8192 fp32
    u16* ci    = us + 51445760;              //  canonical bf16 weights

    u16* w_qkv   = ci;                  // 1769472
    u16* w_proj  = ci + 1769472;        // 589824
    u16* w_cqkv  = ci + 2359296;        // 1769472
    u16* w_cproj = ci + 4128768;        // 589824
    u16* w_cpf1  = ci + 4718592;        // 4096
    u16* w_cpf2  = ci + 4722688;        // 49152
    u16* w_fc1   = ci + 4771840;        // 2359296
    u16* w_fc2   = ci + 7131136;        // 2359296

    // 0. canonicalize weight matrices fp32 -> bf16
    const float* wsrc[8] = { qkv_w, proj_w, c_qkv_w, c_proj_w,
                             cp_fc1_w, cp_fc2_w, fc1_w, fc2_w };
    u16* wdst[8] = { w_qkv, w_proj, w_cqkv, w_cproj,
                     w_cpf1, w_cpf2, w_fc1, w_fc2 };
    const int wn[8] = { 1769472, 589824, 1769472, 589824,
                        4096, 49152, 2359296, 2359296 };
    for (int i = 0; i < 8; i++)
        conv_k<<<(wn[i] / 4 + 255) / 256, 256, 0, stream>>>(wsrc[i], wdst[i], wn[i]);

    // 1. normalize P rows
    pn_k<<<64, 256, 0, stream>>>(P, Pn);
    // 2. n1 = LN(x), invn = 1/||n1||
    ln_k<true><<<8192, 256, 0, stream>>>(x, ln1_g, ln1_b, n1n2, invn);
    // 3. qkv = n1 @ qkv_w^T + qkv_b
    gemm_mfma<F_BIAS | F_OUTB>
        <<<dim3(18, 64), 256, 0, stream>>>(n1n2, w_qkv, qkv_b, nullptr, nullptr,
                                           bigA, nullptr, 8192, 2304, 768);
    // 4. attention 1
    attn_mfma<<<dim3(8, 96), 256, 0, stream>>>(bigA, ao);
    // 5. y = ao @ proj_w^T + proj_b
    gemm_mfma<F_BIAS | F_OUTB>
        <<<dim3(6, 64), 256, 0, stream>>>(ao, w_proj, proj_b, nullptr, nullptr,
                                          y, nullptr, 8192, 768, 768);
    // 6. dmap = (n1 @ Pn^T) * invn  -> dmapb bf16 + out_dmap fp32
    gemm_k<64, 64, F_ROWSCALE | F_OUTB | F_OUTF>
        <<<dim3(1, 128), 256, 0, stream>>>(n1n2, Pn, nullptr, invn, nullptr,
                                           nullptr, dmapb, out_dmap, 8192, 64, 768);
    // 7. cph = gelu(dmap @ cp_fc1_w^T + b)
    gemm_k<64, 64, F_BIAS | F_GELU | F_OUTB>
        <<<dim3(1, 128), 256, 0, stream>>>(dmapb, w_cpf1, cp_fc1_b, nullptr,
                                           nullptr, nullptr, cph, nullptr, 8192, 64, 64);
    // 8. zin = cph @ cp_fc2_w^T + b   (zin aliases n1n2)
    gemm_mfma<F_BIAS | F_OUTB>
        <<<dim3(6, 64), 256, 0, stream>>>(cph, w_cpf2, cp_fc2_b, nullptr, nullptr,
                                          n1n2, nullptr, 8192, 768, 64);
    // 9. qkv2 = zin @ c_qkv_w^T + b
    gemm_mfma<F_BIAS | F_OUTB>
        <<<dim3(18, 64), 256, 0, stream>>>(n1n2, w_cqkv, c_qkv_b, nullptr, nullptr,
                                           bigA, nullptr, 8192, 2304, 768);
    // 10. attention 2
    attn_mfma<<<dim3(8, 96), 256, 0, stream>>>(bigA, ao);
    // 11. xs = ao2 @ c_proj_w^T + b + y + x   (y bf16, x fp32) -> fp32
    gemm_mfma<F_BIAS | F_RES1 | F_RESF | F_OUTF>
        <<<dim3(6, 64), 256, 0, stream>>>(ao, w_cproj, c_proj_b, y, x,
                                          nullptr, xs, 8192, 768, 768);
    // 12. n2 = LN(xs)
    ln_k<false><<<8192, 256, 0, stream>>>(xs, ln2_g, ln2_b, n1n2, nullptr);
    // 13. h = gelu(n2 @ fc1_w^T + b)
    gemm_mfma<F_BIAS | F_GELU | F_OUTB>
        <<<dim3(24, 64), 256, 0, stream>>>(n1n2, w_fc1, fc1_b, nullptr, nullptr,
                                           bigA, nullptr, 8192, 3072, 768);
    // 14. out = h @ fc2_w^T + b + xs  -> fp32 d_out
    gemm_mfma<F_BIAS | F_RESF | F_OUTF>
        <<<dim3(6, 64), 256, 0, stream>>>(bigA, w_fc2, fc2_b, nullptr, xs,
                                          nullptr, out_x, 8192, 768, 3072);
}

// Round 8
// 648.163 us; speedup vs baseline: 1.1735x; 1.1735x over previous
//
#include <hip/hip_runtime.h>

// ---------------------------------------------------------------------------
// Transformer block w/ SimilarityMaps branch. fp32 inputs/outputs; weights
// canonicalized to bf16; GEMMs + attention on MFMA (16x16x32 bf16).
// B=8 N=1024 C=768 H=12 hd=64 K_PARTS=64 HID=3072. Tokens M = 8192.
// Round 7: wave-private incremental LDS-repack epilogue (no barriers, low VGPR).
// ---------------------------------------------------------------------------

typedef unsigned short u16;
typedef unsigned int   u32;
typedef __attribute__((ext_vector_type(8))) short short8;       // bf16 x8 frag
typedef __attribute__((ext_vector_type(8))) unsigned short ushort8v;
typedef __attribute__((ext_vector_type(4))) float f32x4;        // MFMA accum

#define F_GELU     1
#define F_ROWSCALE 2
#define F_RES1     4    // bf16 residual (res1)
#define F_RESF     8    // fp32 residual (resf)
#define F_OUTB     16   // write bf16 to out
#define F_OUTF     32   // write fp32 to outf
#define F_BIAS     64   // fp32 bias

__device__ __forceinline__ float bf2f(u32 b) { return __uint_as_float(b << 16); }
__device__ __forceinline__ u16 f2bf(float f) {
    u32 u = __float_as_uint(f);
    u32 r = u + 0x7fffu + ((u >> 16) & 1u);   // RNE
    return (u16)(r >> 16);
}
__device__ __forceinline__ u16 f2bf_fast(float f) {
    return (u16)((__float_as_uint(f) + 0x8000u) >> 16);
}
__device__ __forceinline__ float gelu_exact(float v) {
    return 0.5f * v * (1.0f + erff(v * 0.70710678118654752440f));
}

// async global->LDS, 16 B per lane; lds base must be wave-uniform
__device__ __forceinline__ void gload16(const u16* g, u16* l) {
    __builtin_amdgcn_global_load_lds(
        (const __attribute__((address_space(1))) u32*)g,
        (__attribute__((address_space(3))) u32*)l, 16, 0, 0);
}

// ---------------- fp32 -> bf16 weight canonicalization ---------------------
__global__ __launch_bounds__(256)
void conv_k(const float* __restrict__ src, u16* __restrict__ dst, int n)
{
    const int base = (blockIdx.x * 256 + threadIdx.x) * 4;
    if (base >= n) return;
    float4 v = *(const float4*)(src + base);
    ushort4 o;
    o.x = f2bf(v.x); o.y = f2bf(v.y); o.z = f2bf(v.z); o.w = f2bf(v.w);
    *(ushort4*)(dst + base) = o;
}

__device__ __forceinline__ float block_sum(float v, float* red) {
    #pragma unroll
    for (int off = 32; off > 0; off >>= 1) v += __shfl_down(v, off);
    __syncthreads();
    if ((threadIdx.x & 63) == 0) red[threadIdx.x >> 6] = v;
    __syncthreads();
    return red[0] + red[1] + red[2] + red[3];
}

// ---------------- LayerNorm over 768 (fp32 in, bf16 out), opt 1/||y|| ------
template<bool NORM>
__global__ __launch_bounds__(256)
void ln_k(const float* __restrict__ xin, const float* __restrict__ g,
          const float* __restrict__ bta, u16* __restrict__ out,
          float* __restrict__ invnorm)
{
    __shared__ float red[4];
    const int row = blockIdx.x, t = threadIdx.x;
    float v[3];
    #pragma unroll
    for (int i = 0; i < 3; i++)
        v[i] = xin[(size_t)row * 768 + t + i * 256];
    float tot = block_sum(v[0] + v[1] + v[2], red);
    float mu  = tot * (1.0f / 768.0f);
    float d0 = v[0] - mu, d1 = v[1] - mu, d2 = v[2] - mu;
    float tot2 = block_sum(d0 * d0 + d1 * d1 + d2 * d2, red);
    float rstd = rsqrtf(tot2 * (1.0f / 768.0f) + 1e-5f);
    float ss = 0.0f;
    #pragma unroll
    for (int i = 0; i < 3; i++) {
        int c = t + i * 256;
        float yy = (v[i] - mu) * rstd * g[c] + bta[c];
        out[(size_t)row * 768 + c] = f2bf(yy);
        ss += yy * yy;
    }
    if constexpr (NORM) {
        float tot3 = block_sum(ss, red);
        if (t == 0) invnorm[row] = rsqrtf(tot3);
    }
}

// ---------------- P row-normalize: Pn = bf16(P / ||P_row||) ----------------
__global__ __launch_bounds__(256)
void pn_k(const float* __restrict__ P, u16* __restrict__ Pn)
{
    __shared__ float red[4];
    const int row = blockIdx.x, t = threadIdx.x;
    float v[3];
    #pragma unroll
    for (int i = 0; i < 3; i++)
        v[i] = P[(size_t)row * 768 + t + i * 256];
    float tot = block_sum(v[0]*v[0] + v[1]*v[1] + v[2]*v[2], red);
    float inv = rsqrtf(tot);
    #pragma unroll
    for (int i = 0; i < 3; i++)
        Pn[(size_t)row * 768 + t + i * 256] = f2bf(v[i] * inv);
}

// ---------------- MFMA GEMM: C[M,N] = A[M,K] * W[N,K]^T (+epilogue) --------
// 128x128 tile, BK=32; 4 waves, each a 64x64 sub-tile.
// Epilogue: wave-private fp32 LDS repack, one 16x64 row-block at a time.
template<int FLAGS>
__global__ __launch_bounds__(256)
void gemm_mfma(const u16* __restrict__ A, const u16* __restrict__ W,
               const float* __restrict__ bias,
               const u16* __restrict__ res1, const float* __restrict__ resf,
               u16* __restrict__ out, float* __restrict__ outf,
               int M, int N, int K)
{
    __shared__ u16 smem[8192];           // staging: As[0:4096) Bs[4096:8192)
                                         // epilogue: 4 waves x 16x64 fp32
    const int t = threadIdx.x;
    const int wave = t >> 6, lane = t & 63;
    const int m0 = blockIdx.y * 128, n0 = blockIdx.x * 128;
    const int Wm = (wave >> 1) * 64, Wn = (wave & 1) * 64;
    const int rr = lane >> 2, cc = (lane & 3) * 8;
    const int quad = lane >> 4, r16 = lane & 15;

    f32x4 acc[4][4];
    #pragma unroll
    for (int i = 0; i < 4; i++)
        #pragma unroll
        for (int j = 0; j < 4; j++)
            acc[i][j] = (f32x4){0.f, 0.f, 0.f, 0.f};

    for (int k0 = 0; k0 < K; k0 += 32) {
        #pragma unroll
        for (int c = 0; c < 2; c++) {
            const int chunk = wave * 2 + c;
            const int row = chunk * 16 + rr;
            gload16(A + (size_t)(m0 + row) * K + k0 + cc, &smem[chunk * 512]);
            gload16(W + (size_t)(n0 + row) * K + k0 + cc, &smem[4096 + chunk * 512]);
        }
        __syncthreads();
        short8 af[4], bfr[4];
        #pragma unroll
        for (int i = 0; i < 4; i++) {
            af[i]  = *(const short8*)&smem[(Wm + i * 16 + r16) * 32 + quad * 8];
            bfr[i] = *(const short8*)&smem[4096 + (Wn + i * 16 + r16) * 32 + quad * 8];
        }
        #pragma unroll
        for (int i = 0; i < 4; i++)
            #pragma unroll
            for (int j = 0; j < 4; j++)
                acc[i][j] = __builtin_amdgcn_mfma_f32_16x16x32_bf16(
                    af[i], bfr[j], acc[i][j], 0, 0, 0);
        __syncthreads();
    }

    // ---- epilogue: wave-private fp32 repack (no cross-wave sync) ----
    float* myl = (float*)smem + wave * 1024;   // 16 rows x 64 cols fp32
    float bj[4];
    #pragma unroll
    for (int j = 0; j < 4; j++) {
        if constexpr (FLAGS & F_BIAS) bj[j] = bias[n0 + Wn + j * 16 + r16];
        else bj[j] = 0.0f;
    }
    const int row = lane >> 2, seg = (lane & 3) * 16;

    #pragma unroll
    for (int i = 0; i < 4; i++) {
        #pragma unroll
        for (int j = 0; j < 4; j++)
            #pragma unroll
            for (int r = 0; r < 4; r++) {
                float v = acc[i][j][r] + bj[j];
                if constexpr (FLAGS & F_GELU) v = gelu_exact(v);
                myl[(quad * 4 + r) * 64 + j * 16 + r16] = v;
            }
        // in-wave readback (lockstep; lgkmcnt ordering by compiler)
        float v[16];
        #pragma unroll
        for (int k4 = 0; k4 < 4; k4++) {
            float4 f = *(const float4*)&myl[row * 64 + seg + k4 * 4];
            v[k4 * 4 + 0] = f.x; v[k4 * 4 + 1] = f.y;
            v[k4 * 4 + 2] = f.z; v[k4 * 4 + 3] = f.w;
        }
        const int m = m0 + Wm + i * 16 + row;
        const size_t idx = (size_t)m * N + n0 + Wn + seg;
        if constexpr (FLAGS & F_RES1) {
            ushort8v r0 = *(const ushort8v*)(res1 + idx);
            ushort8v r1 = *(const ushort8v*)(res1 + idx + 8);
            #pragma unroll
            for (int k = 0; k < 8; k++) { v[k] += bf2f(r0[k]); v[k + 8] += bf2f(r1[k]); }
        }
        if constexpr (FLAGS & F_RESF) {
            #pragma unroll
            for (int k4 = 0; k4 < 4; k4++) {
                float4 f = *(const float4*)(resf + idx + k4 * 4);
                v[k4 * 4 + 0] += f.x; v[k4 * 4 + 1] += f.y;
                v[k4 * 4 + 2] += f.z; v[k4 * 4 + 3] += f.w;
            }
        }
        if constexpr (FLAGS & F_OUTB) {
            ushort8v o0, o1;
            #pragma unroll
            for (int k = 0; k < 8; k++) { o0[k] = f2bf(v[k]); o1[k] = f2bf(v[k + 8]); }
            *(ushort8v*)(out + idx) = o0;
            *(ushort8v*)(out + idx + 8) = o1;
        }
        if constexpr (FLAGS & F_OUTF) {
            #pragma unroll
            for (int k4 = 0; k4 < 4; k4++) {
                float4 f = {v[k4 * 4 + 0], v[k4 * 4 + 1], v[k4 * 4 + 2], v[k4 * 4 + 3]};
                *(float4*)(outf + idx + k4 * 4) = f;
            }
        }
    }
}

// ---------------- small fp32 GEMM (64x64 tiles) for the K-parts branch -----
template<int BM, int BN, int FLAGS>
__global__ __launch_bounds__(256)
void gemm_k(const u16* __restrict__ A, const u16* __restrict__ W,
            const float* __restrict__ bias, const float* __restrict__ rowscale,
            const u16* __restrict__ res1, const float* __restrict__ resf,
            u16* __restrict__ out, float* __restrict__ outf,
            int M, int N, int K)
{
    constexpr int RM = BM / 16, RN = BN / 16;
    __shared__ float Asm[16][BM + 4];
    __shared__ float Wsm[16][BN + 4];
    const int t  = threadIdx.x;
    const int tx = t & 15, ty = t >> 4;
    const int m0 = blockIdx.y * BM, n0 = blockIdx.x * BN;

    float acc[RM][RN];
    #pragma unroll
    for (int i = 0; i < RM; i++)
        #pragma unroll
        for (int j = 0; j < RN; j++) acc[i][j] = 0.0f;

    for (int k0 = 0; k0 < K; k0 += 16) {
        #pragma unroll
        for (int i = 0; i < BM / 64; i++) {
            int f = t + i * 256, r = f >> 2, c4 = (f & 3) << 2;
            uint2 u = *(const uint2*)(A + (size_t)(m0 + r) * K + k0 + c4);
            Asm[c4 + 0][r] = bf2f(u.x & 0xffffu);
            Asm[c4 + 1][r] = bf2f(u.x >> 16);
            Asm[c4 + 2][r] = bf2f(u.y & 0xffffu);
            Asm[c4 + 3][r] = bf2f(u.y >> 16);
        }
        #pragma unroll
        for (int i = 0; i < BN / 64; i++) {
            int f = t + i * 256, r = f >> 2, c4 = (f & 3) << 2;
            uint2 u = *(const uint2*)(W + (size_t)(n0 + r) * K + k0 + c4);
            Wsm[c4 + 0][r] = bf2f(u.x & 0xffffu);
            Wsm[c4 + 1][r] = bf2f(u.x >> 16);
            Wsm[c4 + 2][r] = bf2f(u.y & 0xffffu);
            Wsm[c4 + 3][r] = bf2f(u.y >> 16);
        }
        __syncthreads();
        #pragma unroll
        for (int k = 0; k < 16; k++) {
            float a[RM], w[RN];
            #pragma unroll
            for (int ii = 0; ii < RM; ii += 4) {
                float4 v = *(const float4*)&Asm[k][ty * RM + ii];
                a[ii] = v.x; a[ii + 1] = v.y; a[ii + 2] = v.z; a[ii + 3] = v.w;
            }
            #pragma unroll
            for (int jj = 0; jj < RN; jj += 4) {
                float4 v = *(const float4*)&Wsm[k][tx * RN + jj];
                w[jj] = v.x; w[jj + 1] = v.y; w[jj + 2] = v.z; w[jj + 3] = v.w;
            }
            #pragma unroll
            for (int i = 0; i < RM; i++)
                #pragma unroll
                for (int j = 0; j < RN; j++)
                    acc[i][j] = fmaf(a[i], w[j], acc[i][j]);
        }
        __syncthreads();
    }

    #pragma unroll
    for (int i = 0; i < RM; i++) {
        const int m = m0 + ty * RM + i;
        float rs = 1.0f;
        if constexpr (FLAGS & F_ROWSCALE) rs = rowscale[m];
        #pragma unroll
        for (int jj = 0; jj < RN; jj += 4) {
            const int n = n0 + tx * RN + jj;
            const size_t idx = (size_t)m * N + n;
            float b4[4] = {0.f, 0.f, 0.f, 0.f};
            if constexpr (FLAGS & F_BIAS) {
                float4 bvv = *(const float4*)(bias + n);
                b4[0] = bvv.x; b4[1] = bvv.y; b4[2] = bvv.z; b4[3] = bvv.w;
            }
            float e[4];
            #pragma unroll
            for (int j = 0; j < 4; j++) {
                float v = acc[i][jj + j];
                if constexpr (FLAGS & F_BIAS) v += b4[j];
                if constexpr (FLAGS & F_GELU) v = gelu_exact(v);
                if constexpr (FLAGS & F_ROWSCALE) v *= rs;
                e[j] = v;
            }
            if constexpr (FLAGS & F_OUTB) {
                ushort4 o4;
                o4.x = f2bf(e[0]); o4.y = f2bf(e[1]);
                o4.z = f2bf(e[2]); o4.w = f2bf(e[3]);
                *(ushort4*)(out + idx) = o4;
            }
            if constexpr (FLAGS & F_OUTF) {
                float4 o4 = {e[0], e[1], e[2], e[3]};
                *(float4*)(outf + idx) = o4;
            }
        }
    }
}

// ---------------- MFMA flash attention (bf16, max-free online softmax) ----
__global__ __launch_bounds__(256)
void attn_mfma(const u16* __restrict__ qkv, u16* __restrict__ out)
{
    const int qt = blockIdx.x;            // 0..7  (128-row q tiles)
    const int bh = blockIdx.y;            // 0..95
    const int b = bh / 12, h = bh % 12;
    __shared__ u16 Qs[2 * 128 * 32];      // 16 KB
    __shared__ u16 Ks[2 * 64 * 32];       //  8 KB
    __shared__ u16 Vt[2 * 64 * 32];       //  8 KB  (transposed: rows = d)
    __shared__ u16 Ps[2 * 128 * 32];      // 16 KB; epilogue: 4 waves x 2 x 16x64
    const int t = threadIdx.x;
    const int wave = t >> 6, lane = t & 63;
    const int quad = lane >> 4, r16 = lane & 15;
    const size_t RS = 2304;
    const int tok0 = b * 1024 + qt * 128;
    const u16* qbase = qkv + (size_t)tok0 * RS + h * 64;
    const float SC = 0.125f * 1.44269504088896340736f;   // scale * log2(e)

    #pragma unroll
    for (int c = 0; c < 4; c++) {
        int idx = wave * 4 + c;
        int kc = idx >> 3, rg = idx & 7;
        int row = rg * 16 + (lane >> 2);
        gload16(qbase + (size_t)row * RS + kc * 32 + (lane & 3) * 8,
                &Qs[kc * 4096 + rg * 512]);
    }

    f32x4 O[2][4];
    float lpart[2][4];
    #pragma unroll
    for (int i = 0; i < 2; i++)
        #pragma unroll
        for (int j = 0; j < 4; j++) {
            O[i][j] = (f32x4){0.f, 0.f, 0.f, 0.f};
            lpart[i][j & 3] = 0.0f;
        }

    for (int kt = 0; kt < 16; kt++) {
        const u16* kbase = qkv + (size_t)(b * 1024 + kt * 64) * RS + 768 + h * 64;
        #pragma unroll
        for (int c = 0; c < 2; c++) {
            int idx = wave * 2 + c;
            int kc = idx >> 2, rg = idx & 3;
            int row = rg * 16 + (lane >> 2);
            gload16(kbase + (size_t)row * RS + kc * 32 + (lane & 3) * 8,
                    &Ks[kc * 2048 + rg * 512]);
        }
        const u16* vbase = qkv + (size_t)(b * 1024 + kt * 64) * RS + 1536 + h * 64;
        {
            const int kp = t & 63, dg = t >> 6;
            const int vb = (kp >> 5) * 2048 + (kp & 31);
            #pragma unroll
            for (int it = 0; it < 4; it++) {
                int d0 = dg * 16 + it * 4;
                uint2 u = *(const uint2*)(vbase + (size_t)kp * RS + d0);
                Vt[vb + (d0 + 0) * 32] = (u16)(u.x & 0xffffu);
                Vt[vb + (d0 + 1) * 32] = (u16)(u.x >> 16);
                Vt[vb + (d0 + 2) * 32] = (u16)(u.y & 0xffffu);
                Vt[vb + (d0 + 3) * 32] = (u16)(u.y >> 16);
            }
        }
        __syncthreads();

        f32x4 S[2][4];
        #pragma unroll
        for (int i = 0; i < 2; i++)
            #pragma unroll
            for (int j = 0; j < 4; j++)
                S[i][j] = (f32x4){0.f, 0.f, 0.f, 0.f};
        #pragma unroll
        for (int kc = 0; kc < 2; kc++) {
            short8 aq[2], bk[4];
            #pragma unroll
            for (int i = 0; i < 2; i++)
                aq[i] = *(const short8*)&Qs[kc * 4096 + (wave * 32 + i * 16 + r16) * 32 + quad * 8];
            #pragma unroll
            for (int j = 0; j < 4; j++)
                bk[j] = *(const short8*)&Ks[kc * 2048 + (j * 16 + r16) * 32 + quad * 8];
            #pragma unroll
            for (int i = 0; i < 2; i++)
                #pragma unroll
                for (int j = 0; j < 4; j++)
                    S[i][j] = __builtin_amdgcn_mfma_f32_16x16x32_bf16(
                        aq[i], bk[j], S[i][j], 0, 0, 0);
        }

        #pragma unroll
        for (int i = 0; i < 2; i++) {
            #pragma unroll
            for (int j = 0; j < 4; j++) {
                const int col = j * 16 + r16;
                const int pb = (col >> 5) * 4096 + (col & 31);
                #pragma unroll
                for (int r = 0; r < 4; r++) {
                    float p = __builtin_amdgcn_exp2f(S[i][j][r] * SC);
                    lpart[i][r] += p;
                    const int row = wave * 32 + i * 16 + quad * 4 + r;
                    Ps[pb + row * 32] = f2bf_fast(p);
                }
            }
        }

        #pragma unroll
        for (int kc = 0; kc < 2; kc++) {
            short8 ap[2], bv[4];
            #pragma unroll
            for (int i = 0; i < 2; i++)
                ap[i] = *(const short8*)&Ps[kc * 4096 + (wave * 32 + i * 16 + r16) * 32 + quad * 8];
            #pragma unroll
            for (int j = 0; j < 4; j++)
                bv[j] = *(const short8*)&Vt[kc * 2048 + (j * 16 + r16) * 32 + quad * 8];
            #pragma unroll
            for (int i = 0; i < 2; i++)
                #pragma unroll
                for (int j = 0; j < 4; j++)
                    O[i][j] = __builtin_amdgcn_mfma_f32_16x16x32_bf16(
                        ap[i], bv[j], O[i][j], 0, 0, 0);
        }
        __syncthreads();
    }

    // epilogue: wave-private repack through Ps (dead), coalesced 16B stores
    const int row = lane >> 2, seg = (lane & 3) * 16;
    #pragma unroll
    for (int i = 0; i < 2; i++) {
        float linv[4];
        #pragma unroll
        for (int r = 0; r < 4; r++) {
            float l = lpart[i][r];
            l += __shfl_xor(l, 1);
            l += __shfl_xor(l, 2);
            l += __shfl_xor(l, 4);
            l += __shfl_xor(l, 8);
            linv[r] = 1.0f / l;
        }
        u16* myl = &Ps[wave * 2048 + i * 1024];   // 16 rows x 64 cols
        #pragma unroll
        for (int j = 0; j < 4; j++)
            #pragma unroll
            for (int r = 0; r < 4; r++)
                myl[(quad * 4 + r) * 64 + j * 16 + r16] = f2bf(O[i][j][r] * linv[r]);
        const int token = tok0 + wave * 32 + i * 16 + row;
        const size_t oidx = (size_t)token * 768 + h * 64 + seg;
        *(ushort8v*)(out + oidx)     = *(const ushort8v*)&myl[row * 64 + seg];
        *(ushort8v*)(out + oidx + 8) = *(const ushort8v*)&myl[row * 64 + seg + 8];
    }
}

// ---------------------------------------------------------------------------
extern "C" void kernel_launch(void* const* d_in, const int* in_sizes, int n_in,
                              void* d_out, int out_size, void* d_ws, size_t ws_size,
                              hipStream_t stream)
{
    (void)in_sizes; (void)n_in; (void)out_size; (void)ws_size;
    const float* x        = (const float*)d_in[0];
    const float* ln1_g    = (const float*)d_in[1];
    const float* ln1_b    = (const float*)d_in[2];
    const float* qkv_w    = (const float*)d_in[3];
    const float* qkv_b    = (const float*)d_in[4];
    const float* proj_w   = (const float*)d_in[5];
    const float* proj_b   = (const float*)d_in[6];
    const float* c_qkv_w  = (const float*)d_in[7];
    const float* c_qkv_b  = (const float*)d_in[8];
    const float* c_proj_w = (const float*)d_in[9];
    const float* c_proj_b = (const float*)d_in[10];
    const float* cp_fc1_w = (const float*)d_in[11];
    const float* cp_fc1_b = (const float*)d_in[12];
    const float* cp_fc2_w = (const float*)d_in[13];
    const float* cp_fc2_b = (const float*)d_in[14];
    const float* P        = (const float*)d_in[15];
    const float* ln2_g    = (const float*)d_in[16];
    const float* ln2_b    = (const float*)d_in[17];
    const float* fc1_w    = (const float*)d_in[18];
    const float* fc1_b    = (const float*)d_in[19];
    const float* fc2_w    = (const float*)d_in[20];
    const float* fc2_b    = (const float*)d_in[21];

    float* out_x    = (float*)d_out;               // (8,1024,768) fp32
    float* out_dmap = out_x + 6291456;             // (8,1024,64)  fp32

    // ws layout (u16 element units)
    u16* us    = (u16*)d_ws;
    u16* n1n2  = us;                         //  6291456  n1 -> zin -> n2
    u16* bigA  = us + 6291456;               // 25165824  qkv/qkv2 ; h(3072)
    u16* ao    = bigA + 18874368;            //  6291456  attn out (tail)
    u16* y     = us + 31457280;              //  6291456
    float* xs  = (float*)(us + 37748736);    //  6291456 fp32
    u16* dmapb = us + 50331648;              //   524288
    u16* cph   = us + 50855936;              //   524288
    u16* Pn    = us + 51380224;              //    49152
    float* invn = (float*)(us + 51429376);   //  8192 fp32
    u16* ci    = us + 51445760;              //  canonical bf16 weights

    u16* w_qkv   = ci;                  // 1769472
    u16* w_proj  = ci + 1769472;        // 589824
    u16* w_cqkv  = ci + 2359296;        // 1769472
    u16* w_cproj = ci + 4128768;        // 589824
    u16* w_cpf1  = ci + 4718592;        // 4096
    u16* w_cpf2  = ci + 4722688;        // 49152
    u16* w_fc1   = ci + 4771840;        // 2359296
    u16* w_fc2   = ci + 7131136;        // 2359296

    // 0. canonicalize weight matrices fp32 -> bf16
    const float* wsrc[8] = { qkv_w, proj_w, c_qkv_w, c_proj_w,
                             cp_fc1_w, cp_fc2_w, fc1_w, fc2_w };
    u16* wdst[8] = { w_qkv, w_proj, w_cqkv, w_cproj,
                     w_cpf1, w_cpf2, w_fc1, w_fc2 };
    const int wn[8] = { 1769472, 589824, 1769472, 589824,
                        4096, 49152, 2359296, 2359296 };
    for (int i = 0; i < 8; i++)
        conv_k<<<(wn[i] / 4 + 255) / 256, 256, 0, stream>>>(wsrc[i], wdst[i], wn[i]);

    // 1. normalize P rows
    pn_k<<<64, 256, 0, stream>>>(P, Pn);
    // 2. n1 = LN(x), invn = 1/||n1||
    ln_k<true><<<8192, 256, 0, stream>>>(x, ln1_g, ln1_b, n1n2, invn);
    // 3. qkv = n1 @ qkv_w^T + qkv_b
    gemm_mfma<F_BIAS | F_OUTB>
        <<<dim3(18, 64), 256, 0, stream>>>(n1n2, w_qkv, qkv_b, nullptr, nullptr,
                                           bigA, nullptr, 8192, 2304, 768);
    // 4. attention 1
    attn_mfma<<<dim3(8, 96), 256, 0, stream>>>(bigA, ao);
    // 5. y = ao @ proj_w^T + proj_b
    gemm_mfma<F_BIAS | F_OUTB>
        <<<dim3(6, 64), 256, 0, stream>>>(ao, w_proj, proj_b, nullptr, nullptr,
                                          y, nullptr, 8192, 768, 768);
    // 6. dmap = (n1 @ Pn^T) * invn  -> dmapb bf16 + out_dmap fp32
    gemm_k<64, 64, F_ROWSCALE | F_OUTB | F_OUTF>
        <<<dim3(1, 128), 256, 0, stream>>>(n1n2, Pn, nullptr, invn, nullptr,
                                           nullptr, dmapb, out_dmap, 8192, 64, 768);
    // 7. cph = gelu(dmap @ cp_fc1_w^T + b)
    gemm_k<64, 64, F_BIAS | F_GELU | F_OUTB>
        <<<dim3(1, 128), 256, 0, stream>>>(dmapb, w_cpf1, cp_fc1_b, nullptr,
                                           nullptr, nullptr, cph, nullptr, 8192, 64, 64);
    // 8. zin = cph @ cp_fc2_w^T + b   (zin aliases n1n2)
    gemm_mfma<F_BIAS | F_OUTB>
        <<<dim3(6, 64), 256, 0, stream>>>(cph, w_cpf2, cp_fc2_b, nullptr, nullptr,
                                          n1n2, nullptr, 8192, 768, 64);
    // 9. qkv2 = zin @ c_qkv_w^T + b
    gemm_mfma<F_BIAS | F_OUTB>
        <<<dim3(18, 64), 256, 0, stream>>>(n1n2, w_cqkv, c_qkv_b, nullptr, nullptr,
                                           bigA, nullptr, 8192, 2304, 768);
    // 10. attention 2
    attn_mfma<<<dim3(8, 96), 256, 0, stream>>>(bigA, ao);
    // 11. xs = ao2 @ c_proj_w^T + b + y + x   (y bf16, x fp32) -> fp32
    gemm_mfma<F_BIAS | F_RES1 | F_RESF | F_OUTF>
        <<<dim3(6, 64), 256, 0, stream>>>(ao, w_cproj, c_proj_b, y, x,
                                          nullptr, xs, 8192, 768, 768);
    // 12. n2 = LN(xs)
    ln_k<false><<<8192, 256, 0, stream>>>(xs, ln2_g, ln2_b, n1n2, nullptr);
    // 13. h = gelu(n2 @ fc1_w^T + b)
    gemm_mfma<F_BIAS | F_GELU | F_OUTB>
        <<<dim3(24, 64), 256, 0, stream>>>(n1n2, w_fc1, fc1_b, nullptr, nullptr,
                                           bigA, nullptr, 8192, 3072, 768);
    // 14. out = h @ fc2_w^T + b + xs  -> fp32 d_out
    gemm_mfma<F_BIAS | F_RESF | F_OUTF>
        <<<dim3(6, 64), 256, 0, stream>>>(bigA, w_fc2, fc2_b, nullptr, xs,
                                          nullptr, out_x, 8192, 768, 3072);
}

// Round 9
// 595.339 us; speedup vs baseline: 1.2776x; 1.0887x over previous
//
#include <hip/hip_runtime.h>

// ---------------------------------------------------------------------------
// Transformer block w/ SimilarityMaps branch. fp32 inputs/outputs; weights
// canonicalized to bf16; GEMMs + attention on MFMA (16x16x32 bf16).
// B=8 N=1024 C=768 H=12 hd=64 K_PARTS=64 HID=3072. Tokens M = 8192.
// Round 8: double-buffered GEMM K-loop w/ manual vmcnt(4) + raw s_barrier;
//          tanh-form GELU in the MFMA GEMM epilogue.
// ---------------------------------------------------------------------------

typedef unsigned short u16;
typedef unsigned int   u32;
typedef __attribute__((ext_vector_type(8))) short short8;       // bf16 x8 frag
typedef __attribute__((ext_vector_type(8))) unsigned short ushort8v;
typedef __attribute__((ext_vector_type(4))) float f32x4;        // MFMA accum

#define F_GELU     1
#define F_ROWSCALE 2
#define F_RES1     4    // bf16 residual (res1)
#define F_RESF     8    // fp32 residual (resf)
#define F_OUTB     16   // write bf16 to out
#define F_OUTF     32   // write fp32 to outf
#define F_BIAS     64   // fp32 bias

__device__ __forceinline__ float bf2f(u32 b) { return __uint_as_float(b << 16); }
__device__ __forceinline__ u16 f2bf(float f) {
    u32 u = __float_as_uint(f);
    u32 r = u + 0x7fffu + ((u >> 16) & 1u);   // RNE
    return (u16)(r >> 16);
}
__device__ __forceinline__ u16 f2bf_fast(float f) {
    return (u16)((__float_as_uint(f) + 0x8000u) >> 16);
}
__device__ __forceinline__ float gelu_exact(float v) {
    return 0.5f * v * (1.0f + erff(v * 0.70710678118654752440f));
}
// tanh-form GELU (max abs dev from exact ~3e-3; cheap: 1 transcendental)
__device__ __forceinline__ float gelu_fast(float x) {
    float u = 0.79788456080286535588f * (x + 0.044715f * x * x * x);
    float e = __builtin_amdgcn_exp2f(u * 2.88539008177792681472f);  // exp(2u)
    float t = 1.0f - 2.0f / (e + 1.0f);
    return 0.5f * x * (1.0f + t);
}

// async global->LDS, 16 B per lane; lds base must be wave-uniform
__device__ __forceinline__ void gload16(const u16* g, u16* l) {
    __builtin_amdgcn_global_load_lds(
        (const __attribute__((address_space(1))) u32*)g,
        (__attribute__((address_space(3))) u32*)l, 16, 0, 0);
}

// ---------------- fp32 -> bf16 weight canonicalization ---------------------
__global__ __launch_bounds__(256)
void conv_k(const float* __restrict__ src, u16* __restrict__ dst, int n)
{
    const int base = (blockIdx.x * 256 + threadIdx.x) * 4;
    if (base >= n) return;
    float4 v = *(const float4*)(src + base);
    ushort4 o;
    o.x = f2bf(v.x); o.y = f2bf(v.y); o.z = f2bf(v.z); o.w = f2bf(v.w);
    *(ushort4*)(dst + base) = o;
}

__device__ __forceinline__ float block_sum(float v, float* red) {
    #pragma unroll
    for (int off = 32; off > 0; off >>= 1) v += __shfl_down(v, off);
    __syncthreads();
    if ((threadIdx.x & 63) == 0) red[threadIdx.x >> 6] = v;
    __syncthreads();
    return red[0] + red[1] + red[2] + red[3];
}

// ---------------- LayerNorm over 768 (fp32 in, bf16 out), opt 1/||y|| ------
template<bool NORM>
__global__ __launch_bounds__(256)
void ln_k(const float* __restrict__ xin, const float* __restrict__ g,
          const float* __restrict__ bta, u16* __restrict__ out,
          float* __restrict__ invnorm)
{
    __shared__ float red[4];
    const int row = blockIdx.x, t = threadIdx.x;
    float v[3];
    #pragma unroll
    for (int i = 0; i < 3; i++)
        v[i] = xin[(size_t)row * 768 + t + i * 256];
    float tot = block_sum(v[0] + v[1] + v[2], red);
    float mu  = tot * (1.0f / 768.0f);
    float d0 = v[0] - mu, d1 = v[1] - mu, d2 = v[2] - mu;
    float tot2 = block_sum(d0 * d0 + d1 * d1 + d2 * d2, red);
    float rstd = rsqrtf(tot2 * (1.0f / 768.0f) + 1e-5f);
    float ss = 0.0f;
    #pragma unroll
    for (int i = 0; i < 3; i++) {
        int c = t + i * 256;
        float yy = (v[i] - mu) * rstd * g[c] + bta[c];
        out[(size_t)row * 768 + c] = f2bf(yy);
        ss += yy * yy;
    }
    if constexpr (NORM) {
        float tot3 = block_sum(ss, red);
        if (t == 0) invnorm[row] = rsqrtf(tot3);
    }
}

// ---------------- P row-normalize: Pn = bf16(P / ||P_row||) ----------------
__global__ __launch_bounds__(256)
void pn_k(const float* __restrict__ P, u16* __restrict__ Pn)
{
    __shared__ float red[4];
    const int row = blockIdx.x, t = threadIdx.x;
    float v[3];
    #pragma unroll
    for (int i = 0; i < 3; i++)
        v[i] = P[(size_t)row * 768 + t + i * 256];
    float tot = block_sum(v[0]*v[0] + v[1]*v[1] + v[2]*v[2], red);
    float inv = rsqrtf(tot);
    #pragma unroll
    for (int i = 0; i < 3; i++)
        Pn[(size_t)row * 768 + t + i * 256] = f2bf(v[i] * inv);
}

// ---------------- MFMA GEMM: C[M,N] = A[M,K] * W[N,K]^T (+epilogue) --------
// 128x128 tile, BK=32; 4 waves, each a 64x64 sub-tile. Double-buffered LDS
// with manual s_waitcnt vmcnt(4) + raw s_barrier (prefetch stays in flight).
template<int FLAGS>
__global__ __launch_bounds__(256)
void gemm_mfma(const u16* __restrict__ A, const u16* __restrict__ W,
               const float* __restrict__ bias,
               const u16* __restrict__ res1, const float* __restrict__ resf,
               u16* __restrict__ out, float* __restrict__ outf,
               int M, int N, int K)
{
    __shared__ u16 smem[2][8192];        // [buf][ As 4096 | Bs 4096 ]
    const int t = threadIdx.x;
    const int wave = t >> 6, lane = t & 63;
    const int m0 = blockIdx.y * 128, n0 = blockIdx.x * 128;
    const int Wm = (wave >> 1) * 64, Wn = (wave & 1) * 64;
    const int rr = lane >> 2, cc = (lane & 3) * 8;
    const int quad = lane >> 4, r16 = lane & 15;
    const int NK = K >> 5;

    f32x4 acc[4][4];
    #pragma unroll
    for (int i = 0; i < 4; i++)
        #pragma unroll
        for (int j = 0; j < 4; j++)
            acc[i][j] = (f32x4){0.f, 0.f, 0.f, 0.f};

    // prologue: stage k-tile 0 into buf 0
    #pragma unroll
    for (int c = 0; c < 2; c++) {
        const int chunk = wave * 2 + c;
        const int row = chunk * 16 + rr;
        gload16(A + (size_t)(m0 + row) * K + cc, &smem[0][chunk * 512]);
        gload16(W + (size_t)(n0 + row) * K + cc, &smem[0][4096 + chunk * 512]);
    }

    for (int kt = 0; kt < NK; kt++) {
        const int cur = kt & 1;
        if (kt + 1 < NK) {
            const int k0 = (kt + 1) * 32;
            #pragma unroll
            for (int c = 0; c < 2; c++) {
                const int chunk = wave * 2 + c;
                const int row = chunk * 16 + rr;
                gload16(A + (size_t)(m0 + row) * K + k0 + cc,
                        &smem[cur ^ 1][chunk * 512]);
                gload16(W + (size_t)(n0 + row) * K + k0 + cc,
                        &smem[cur ^ 1][4096 + chunk * 512]);
            }
            // wait only for the 4 current-tile loads; keep 4 prefetch in flight
            asm volatile("s_waitcnt vmcnt(4)\n\ts_barrier" ::: "memory");
        } else {
            asm volatile("s_waitcnt vmcnt(0)\n\ts_barrier" ::: "memory");
        }
        short8 af[4], bfr[4];
        #pragma unroll
        for (int i = 0; i < 4; i++) {
            af[i]  = *(const short8*)&smem[cur][(Wm + i * 16 + r16) * 32 + quad * 8];
            bfr[i] = *(const short8*)&smem[cur][4096 + (Wn + i * 16 + r16) * 32 + quad * 8];
        }
        #pragma unroll
        for (int i = 0; i < 4; i++)
            #pragma unroll
            for (int j = 0; j < 4; j++)
                acc[i][j] = __builtin_amdgcn_mfma_f32_16x16x32_bf16(
                    af[i], bfr[j], acc[i][j], 0, 0, 0);
        // all waves done reading cur before next iter overwrites it
        asm volatile("s_barrier" ::: "memory");
    }

    // ---- epilogue: wave-private fp32 repack (no cross-wave sync) ----
    float* myl = (float*)&smem[0][0] + wave * 1024;   // 16 rows x 64 cols fp32
    float bj[4];
    #pragma unroll
    for (int j = 0; j < 4; j++) {
        if constexpr (FLAGS & F_BIAS) bj[j] = bias[n0 + Wn + j * 16 + r16];
        else bj[j] = 0.0f;
    }
    const int row = lane >> 2, seg = (lane & 3) * 16;

    #pragma unroll
    for (int i = 0; i < 4; i++) {
        #pragma unroll
        for (int j = 0; j < 4; j++)
            #pragma unroll
            for (int r = 0; r < 4; r++) {
                float v = acc[i][j][r] + bj[j];
                if constexpr (FLAGS & F_GELU) v = gelu_fast(v);
                myl[(quad * 4 + r) * 64 + j * 16 + r16] = v;
            }
        // in-wave readback (lockstep; lgkmcnt ordering by compiler)
        float v[16];
        #pragma unroll
        for (int k4 = 0; k4 < 4; k4++) {
            float4 f = *(const float4*)&myl[row * 64 + seg + k4 * 4];
            v[k4 * 4 + 0] = f.x; v[k4 * 4 + 1] = f.y;
            v[k4 * 4 + 2] = f.z; v[k4 * 4 + 3] = f.w;
        }
        const int m = m0 + Wm + i * 16 + row;
        const size_t idx = (size_t)m * N + n0 + Wn + seg;
        if constexpr (FLAGS & F_RES1) {
            ushort8v r0 = *(const ushort8v*)(res1 + idx);
            ushort8v r1 = *(const ushort8v*)(res1 + idx + 8);
            #pragma unroll
            for (int k = 0; k < 8; k++) { v[k] += bf2f(r0[k]); v[k + 8] += bf2f(r1[k]); }
        }
        if constexpr (FLAGS & F_RESF) {
            #pragma unroll
            for (int k4 = 0; k4 < 4; k4++) {
                float4 f = *(const float4*)(resf + idx + k4 * 4);
                v[k4 * 4 + 0] += f.x; v[k4 * 4 + 1] += f.y;
                v[k4 * 4 + 2] += f.z; v[k4 * 4 + 3] += f.w;
            }
        }
        if constexpr (FLAGS & F_OUTB) {
            ushort8v o0, o1;
            #pragma unroll
            for (int k = 0; k < 8; k++) { o0[k] = f2bf(v[k]); o1[k] = f2bf(v[k + 8]); }
            *(ushort8v*)(out + idx) = o0;
            *(ushort8v*)(out + idx + 8) = o1;
        }
        if constexpr (FLAGS & F_OUTF) {
            #pragma unroll
            for (int k4 = 0; k4 < 4; k4++) {
                float4 f = {v[k4 * 4 + 0], v[k4 * 4 + 1], v[k4 * 4 + 2], v[k4 * 4 + 3]};
                *(float4*)(outf + idx + k4 * 4) = f;
            }
        }
    }
}

// ---------------- small fp32 GEMM (64x64 tiles) for the K-parts branch -----
template<int BM, int BN, int FLAGS>
__global__ __launch_bounds__(256)
void gemm_k(const u16* __restrict__ A, const u16* __restrict__ W,
            const float* __restrict__ bias, const float* __restrict__ rowscale,
            const u16* __restrict__ res1, const float* __restrict__ resf,
            u16* __restrict__ out, float* __restrict__ outf,
            int M, int N, int K)
{
    constexpr int RM = BM / 16, RN = BN / 16;
    __shared__ float Asm[16][BM + 4];
    __shared__ float Wsm[16][BN + 4];
    const int t  = threadIdx.x;
    const int tx = t & 15, ty = t >> 4;
    const int m0 = blockIdx.y * BM, n0 = blockIdx.x * BN;

    float acc[RM][RN];
    #pragma unroll
    for (int i = 0; i < RM; i++)
        #pragma unroll
        for (int j = 0; j < RN; j++) acc[i][j] = 0.0f;

    for (int k0 = 0; k0 < K; k0 += 16) {
        #pragma unroll
        for (int i = 0; i < BM / 64; i++) {
            int f = t + i * 256, r = f >> 2, c4 = (f & 3) << 2;
            uint2 u = *(const uint2*)(A + (size_t)(m0 + r) * K + k0 + c4);
            Asm[c4 + 0][r] = bf2f(u.x & 0xffffu);
            Asm[c4 + 1][r] = bf2f(u.x >> 16);
            Asm[c4 + 2][r] = bf2f(u.y & 0xffffu);
            Asm[c4 + 3][r] = bf2f(u.y >> 16);
        }
        #pragma unroll
        for (int i = 0; i < BN / 64; i++) {
            int f = t + i * 256, r = f >> 2, c4 = (f & 3) << 2;
            uint2 u = *(const uint2*)(W + (size_t)(n0 + r) * K + k0 + c4);
            Wsm[c4 + 0][r] = bf2f(u.x & 0xffffu);
            Wsm[c4 + 1][r] = bf2f(u.x >> 16);
            Wsm[c4 + 2][r] = bf2f(u.y & 0xffffu);
            Wsm[c4 + 3][r] = bf2f(u.y >> 16);
        }
        __syncthreads();
        #pragma unroll
        for (int k = 0; k < 16; k++) {
            float a[RM], w[RN];
            #pragma unroll
            for (int ii = 0; ii < RM; ii += 4) {
                float4 v = *(const float4*)&Asm[k][ty * RM + ii];
                a[ii] = v.x; a[ii + 1] = v.y; a[ii + 2] = v.z; a[ii + 3] = v.w;
            }
            #pragma unroll
            for (int jj = 0; jj < RN; jj += 4) {
                float4 v = *(const float4*)&Wsm[k][tx * RN + jj];
                w[jj] = v.x; w[jj + 1] = v.y; w[jj + 2] = v.z; w[jj + 3] = v.w;
            }
            #pragma unroll
            for (int i = 0; i < RM; i++)
                #pragma unroll
                for (int j = 0; j < RN; j++)
                    acc[i][j] = fmaf(a[i], w[j], acc[i][j]);
        }
        __syncthreads();
    }

    #pragma unroll
    for (int i = 0; i < RM; i++) {
        const int m = m0 + ty * RM + i;
        float rs = 1.0f;
        if constexpr (FLAGS & F_ROWSCALE) rs = rowscale[m];
        #pragma unroll
        for (int jj = 0; jj < RN; jj += 4) {
            const int n = n0 + tx * RN + jj;
            const size_t idx = (size_t)m * N + n;
            float b4[4] = {0.f, 0.f, 0.f, 0.f};
            if constexpr (FLAGS & F_BIAS) {
                float4 bvv = *(const float4*)(bias + n);
                b4[0] = bvv.x; b4[1] = bvv.y; b4[2] = bvv.z; b4[3] = bvv.w;
            }
            float e[4];
            #pragma unroll
            for (int j = 0; j < 4; j++) {
                float v = acc[i][jj + j];
                if constexpr (FLAGS & F_BIAS) v += b4[j];
                if constexpr (FLAGS & F_GELU) v = gelu_exact(v);
                if constexpr (FLAGS & F_ROWSCALE) v *= rs;
                e[j] = v;
            }
            if constexpr (FLAGS & F_OUTB) {
                ushort4 o4;
                o4.x = f2bf(e[0]); o4.y = f2bf(e[1]);
                o4.z = f2bf(e[2]); o4.w = f2bf(e[3]);
                *(ushort4*)(out + idx) = o4;
            }
            if constexpr (FLAGS & F_OUTF) {
                float4 o4 = {e[0], e[1], e[2], e[3]};
                *(float4*)(outf + idx) = o4;
            }
        }
    }
}

// ---------------- MFMA flash attention (bf16, max-free online softmax) ----
__global__ __launch_bounds__(256)
void attn_mfma(const u16* __restrict__ qkv, u16* __restrict__ out)
{
    const int qt = blockIdx.x;            // 0..7  (128-row q tiles)
    const int bh = blockIdx.y;            // 0..95
    const int b = bh / 12, h = bh % 12;
    __shared__ u16 Qs[2 * 128 * 32];      // 16 KB
    __shared__ u16 Ks[2 * 64 * 32];       //  8 KB
    __shared__ u16 Vt[2 * 64 * 32];       //  8 KB  (transposed: rows = d)
    __shared__ u16 Ps[2 * 128 * 32];      // 16 KB; epilogue: 4 waves x 2 x 16x64
    const int t = threadIdx.x;
    const int wave = t >> 6, lane = t & 63;
    const int quad = lane >> 4, r16 = lane & 15;
    const size_t RS = 2304;
    const int tok0 = b * 1024 + qt * 128;
    const u16* qbase = qkv + (size_t)tok0 * RS + h * 64;
    const float SC = 0.125f * 1.44269504088896340736f;   // scale * log2(e)

    #pragma unroll
    for (int c = 0; c < 4; c++) {
        int idx = wave * 4 + c;
        int kc = idx >> 3, rg = idx & 7;
        int row = rg * 16 + (lane >> 2);
        gload16(qbase + (size_t)row * RS + kc * 32 + (lane & 3) * 8,
                &Qs[kc * 4096 + rg * 512]);
    }

    f32x4 O[2][4];
    float lpart[2][4];
    #pragma unroll
    for (int i = 0; i < 2; i++)
        #pragma unroll
        for (int j = 0; j < 4; j++) {
            O[i][j] = (f32x4){0.f, 0.f, 0.f, 0.f};
            lpart[i][j & 3] = 0.0f;
        }

    for (int kt = 0; kt < 16; kt++) {
        const u16* kbase = qkv + (size_t)(b * 1024 + kt * 64) * RS + 768 + h * 64;
        #pragma unroll
        for (int c = 0; c < 2; c++) {
            int idx = wave * 2 + c;
            int kc = idx >> 2, rg = idx & 3;
            int row = rg * 16 + (lane >> 2);
            gload16(kbase + (size_t)row * RS + kc * 32 + (lane & 3) * 8,
                    &Ks[kc * 2048 + rg * 512]);
        }
        const u16* vbase = qkv + (size_t)(b * 1024 + kt * 64) * RS + 1536 + h * 64;
        {
            const int kp = t & 63, dg = t >> 6;
            const int vb = (kp >> 5) * 2048 + (kp & 31);
            #pragma unroll
            for (int it = 0; it < 4; it++) {
                int d0 = dg * 16 + it * 4;
                uint2 u = *(const uint2*)(vbase + (size_t)kp * RS + d0);
                Vt[vb + (d0 + 0) * 32] = (u16)(u.x & 0xffffu);
                Vt[vb + (d0 + 1) * 32] = (u16)(u.x >> 16);
                Vt[vb + (d0 + 2) * 32] = (u16)(u.y & 0xffffu);
                Vt[vb + (d0 + 3) * 32] = (u16)(u.y >> 16);
            }
        }
        __syncthreads();

        f32x4 S[2][4];
        #pragma unroll
        for (int i = 0; i < 2; i++)
            #pragma unroll
            for (int j = 0; j < 4; j++)
                S[i][j] = (f32x4){0.f, 0.f, 0.f, 0.f};
        #pragma unroll
        for (int kc = 0; kc < 2; kc++) {
            short8 aq[2], bk[4];
            #pragma unroll
            for (int i = 0; i < 2; i++)
                aq[i] = *(const short8*)&Qs[kc * 4096 + (wave * 32 + i * 16 + r16) * 32 + quad * 8];
            #pragma unroll
            for (int j = 0; j < 4; j++)
                bk[j] = *(const short8*)&Ks[kc * 2048 + (j * 16 + r16) * 32 + quad * 8];
            #pragma unroll
            for (int i = 0; i < 2; i++)
                #pragma unroll
                for (int j = 0; j < 4; j++)
                    S[i][j] = __builtin_amdgcn_mfma_f32_16x16x32_bf16(
                        aq[i], bk[j], S[i][j], 0, 0, 0);
        }

        #pragma unroll
        for (int i = 0; i < 2; i++) {
            #pragma unroll
            for (int j = 0; j < 4; j++) {
                const int col = j * 16 + r16;
                const int pb = (col >> 5) * 4096 + (col & 31);
                #pragma unroll
                for (int r = 0; r < 4; r++) {
                    float p = __builtin_amdgcn_exp2f(S[i][j][r] * SC);
                    lpart[i][r] += p;
                    const int row = wave * 32 + i * 16 + quad * 4 + r;
                    Ps[pb + row * 32] = f2bf_fast(p);
                }
            }
        }

        #pragma unroll
        for (int kc = 0; kc < 2; kc++) {
            short8 ap[2], bv[4];
            #pragma unroll
            for (int i = 0; i < 2; i++)
                ap[i] = *(const short8*)&Ps[kc * 4096 + (wave * 32 + i * 16 + r16) * 32 + quad * 8];
            #pragma unroll
            for (int j = 0; j < 4; j++)
                bv[j] = *(const short8*)&Vt[kc * 2048 + (j * 16 + r16) * 32 + quad * 8];
            #pragma unroll
            for (int i = 0; i < 2; i++)
                #pragma unroll
                for (int j = 0; j < 4; j++)
                    O[i][j] = __builtin_amdgcn_mfma_f32_16x16x32_bf16(
                        ap[i], bv[j], O[i][j], 0, 0, 0);
        }
        __syncthreads();
    }

    // epilogue: wave-private repack through Ps (dead), coalesced 16B stores
    const int row = lane >> 2, seg = (lane & 3) * 16;
    #pragma unroll
    for (int i = 0; i < 2; i++) {
        float linv[4];
        #pragma unroll
        for (int r = 0; r < 4; r++) {
            float l = lpart[i][r];
            l += __shfl_xor(l, 1);
            l += __shfl_xor(l, 2);
            l += __shfl_xor(l, 4);
            l += __shfl_xor(l, 8);
            linv[r] = 1.0f / l;
        }
        u16* myl = &Ps[wave * 2048 + i * 1024];   // 16 rows x 64 cols
        #pragma unroll
        for (int j = 0; j < 4; j++)
            #pragma unroll
            for (int r = 0; r < 4; r++)
                myl[(quad * 4 + r) * 64 + j * 16 + r16] = f2bf(O[i][j][r] * linv[r]);
        const int token = tok0 + wave * 32 + i * 16 + row;
        const size_t oidx = (size_t)token * 768 + h * 64 + seg;
        *(ushort8v*)(out + oidx)     = *(const ushort8v*)&myl[row * 64 + seg];
        *(ushort8v*)(out + oidx + 8) = *(const ushort8v*)&myl[row * 64 + seg + 8];
    }
}

// ---------------------------------------------------------------------------
extern "C" void kernel_launch(void* const* d_in, const int* in_sizes, int n_in,
                              void* d_out, int out_size, void* d_ws, size_t ws_size,
                              hipStream_t stream)
{
    (void)in_sizes; (void)n_in; (void)out_size; (void)ws_size;
    const float* x        = (const float*)d_in[0];
    const float* ln1_g    = (const float*)d_in[1];
    const float* ln1_b    = (const float*)d_in[2];
    const float* qkv_w    = (const float*)d_in[3];
    const float* qkv_b    = (const float*)d_in[4];
    const float* proj_w   = (const float*)d_in[5];
    const float* proj_b   = (const float*)d_in[6];
    const float* c_qkv_w  = (const float*)d_in[7];
    const float* c_qkv_b  = (const float*)d_in[8];
    const float* c_proj_w = (const float*)d_in[9];
    const float* c_proj_b = (const float*)d_in[10];
    const float* cp_fc1_w = (const float*)d_in[11];
    const float* cp_fc1_b = (const float*)d_in[12];
    const float* cp_fc2_w = (const float*)d_in[13];
    const float* cp_fc2_b = (const float*)d_in[14];
    const float* P        = (const float*)d_in[15];
    const float* ln2_g    = (const float*)d_in[16];
    const float* ln2_b    = (const float*)d_in[17];
    const float* fc1_w    = (const float*)d_in[18];
    const float* fc1_b    = (const float*)d_in[19];
    const float* fc2_w    = (const float*)d_in[20];
    const float* fc2_b    = (const float*)d_in[21];

    float* out_x    = (float*)d_out;               // (8,1024,768) fp32
    float* out_dmap = out_x + 6291456;             // (8,1024,64)  fp32

    // ws layout (u16 element units)
    u16* us    = (u16*)d_ws;
    u16* n1n2  = us;                         //  6291456  n1 -> zin -> n2
    u16* bigA  = us + 6291456;               // 25165824  qkv/qkv2 ; h(3072)
    u16* ao    = bigA + 18874368;            //  6291456  attn out (tail)
    u16* y     = us + 31457280;              //  6291456
    float* xs  = (float*)(us + 37748736);    //  6291456 fp32
    u16* dmapb = us + 50331648;              //   524288
    u16* cph   = us + 50855936;              //   524288
    u16* Pn    = us + 51380224;              //    49152
    float* invn = (float*)(us + 51429376);   //  8192 fp32
    u16* ci    = us + 51445760;              //  canonical bf16 weights

    u16* w_qkv   = ci;                  // 1769472
    u16* w_proj  = ci + 1769472;        // 589824
    u16* w_cqkv  = ci + 2359296;        // 1769472
    u16* w_cproj = ci + 4128768;        // 589824
    u16* w_cpf1  = ci + 4718592;        // 4096
    u16* w_cpf2  = ci + 4722688;        // 49152
    u16* w_fc1   = ci + 4771840;        // 2359296
    u16* w_fc2   = ci + 7131136;        // 2359296

    // 0. canonicalize weight matrices fp32 -> bf16
    const float* wsrc[8] = { qkv_w, proj_w, c_qkv_w, c_proj_w,
                             cp_fc1_w, cp_fc2_w, fc1_w, fc2_w };
    u16* wdst[8] = { w_qkv, w_proj, w_cqkv, w_cproj,
                     w_cpf1, w_cpf2, w_fc1, w_fc2 };
    const int wn[8] = { 1769472, 589824, 1769472, 589824,
                        4096, 49152, 2359296, 2359296 };
    for (int i = 0; i < 8; i++)
        conv_k<<<(wn[i] / 4 + 255) / 256, 256, 0, stream>>>(wsrc[i], wdst[i], wn[i]);

    // 1. normalize P rows
    pn_k<<<64, 256, 0, stream>>>(P, Pn);
    // 2. n1 = LN(x), invn = 1/||n1||
    ln_k<true><<<8192, 256, 0, stream>>>(x, ln1_g, ln1_b, n1n2, invn);
    // 3. qkv = n1 @ qkv_w^T + qkv_b
    gemm_mfma<F_BIAS | F_OUTB>
        <<<dim3(18, 64), 256, 0, stream>>>(n1n2, w_qkv, qkv_b, nullptr, nullptr,
                                           bigA, nullptr, 8192, 2304, 768);
    // 4. attention 1
    attn_mfma<<<dim3(8, 96), 256, 0, stream>>>(bigA, ao);
    // 5. y = ao @ proj_w^T + proj_b
    gemm_mfma<F_BIAS | F_OUTB>
        <<<dim3(6, 64), 256, 0, stream>>>(ao, w_proj, proj_b, nullptr, nullptr,
                                          y, nullptr, 8192, 768, 768);
    // 6. dmap = (n1 @ Pn^T) * invn  -> dmapb bf16 + out_dmap fp32
    gemm_k<64, 64, F_ROWSCALE | F_OUTB | F_OUTF>
        <<<dim3(1, 128), 256, 0, stream>>>(n1n2, Pn, nullptr, invn, nullptr,
                                           nullptr, dmapb, out_dmap, 8192, 64, 768);
    // 7. cph = gelu(dmap @ cp_fc1_w^T + b)
    gemm_k<64, 64, F_BIAS | F_GELU | F_OUTB>
        <<<dim3(1, 128), 256, 0, stream>>>(dmapb, w_cpf1, cp_fc1_b, nullptr,
                                           nullptr, nullptr, cph, nullptr, 8192, 64, 64);
    // 8. zin = cph @ cp_fc2_w^T + b   (zin aliases n1n2)
    gemm_mfma<F_BIAS | F_OUTB>
        <<<dim3(6, 64), 256, 0, stream>>>(cph, w_cpf2, cp_fc2_b, nullptr, nullptr,
                                          n1n2, nullptr, 8192, 768, 64);
    // 9. qkv2 = zin @ c_qkv_w^T + b
    gemm_mfma<F_BIAS | F_OUTB>
        <<<dim3(18, 64), 256, 0, stream>>>(n1n2, w_cqkv, c_qkv_b, nullptr, nullptr,
                                           bigA, nullptr, 8192, 2304, 768);
    // 10. attention 2
    attn_mfma<<<dim3(8, 96), 256, 0, stream>>>(bigA, ao);
    // 11. xs = ao2 @ c_proj_w^T + b + y + x   (y bf16, x fp32) -> fp32
    gemm_mfma<F_BIAS | F_RES1 | F_RESF | F_OUTF>
        <<<dim3(6, 64), 256, 0, stream>>>(ao, w_cproj, c_proj_b, y, x,
                                          nullptr, xs, 8192, 768, 768);
    // 12. n2 = LN(xs)
    ln_k<false><<<8192, 256, 0, stream>>>(xs, ln2_g, ln2_b, n1n2, nullptr);
    // 13. h = gelu(n2 @ fc1_w^T + b)
    gemm_mfma<F_BIAS | F_GELU | F_OUTB>
        <<<dim3(24, 64), 256, 0, stream>>>(n1n2, w_fc1, fc1_b, nullptr, nullptr,
                                           bigA, nullptr, 8192, 3072, 768);
    // 14. out = h @ fc2_w^T + b + xs  -> fp32 d_out
    gemm_mfma<F_BIAS | F_RESF | F_OUTF>
        <<<dim3(6, 64), 256, 0, stream>>>(bigA, w_fc2, fc2_b, nullptr, xs,
                                          nullptr, out_x, 8192, 768, 3072);
}